// Round 9
// baseline (350.757 us; speedup 1.0000x reference)
//
#include <hip/hip_runtime.h>
#include <cstddef>

#define NN 256
#define DD 1024
#define CC 4
#define RS 32              // row-split units per node
#define ROWS (DD / RS)     // 32 rows per unit
#define NB 448             // all blocks resident (2 blocks/CU capacity)
#define LEAVES 32
#define LQUOTA (NB / LEAVES)
#define ROOT (NN - 1)
#define AGT __HIP_MEMORY_SCOPE_AGENT

// Static device scratch. g_z is zeroed at the START of the main kernel (so no
// cross-launch state); g_done/g_tick/barrier state are zeroed by reset_kernel
// launched right after, so every launch/graph-replay starts clean.
__device__ float g_z[NN][DD];        // accumulated z per node (1 MB)
__device__ int g_done[NN];           // completed units per node (0..RS)
__device__ int g_tick;               // global unit ticket
__device__ int g_bar_leaf[LEAVES];   // start-barrier leaf counters
__device__ int g_bar_root;           // start-barrier root counter
__device__ int g_gen[LEAVES][32];    // per-leaf generation words (128B apart)

#define AL(p) __hip_atomic_load((p), __ATOMIC_RELAXED, AGT)
#define ASR(p, v) __hip_atomic_store((p), (v), __ATOMIC_RELAXED, AGT)

__device__ __forceinline__ void grid_bar(int gen, int leaf) {
  __syncthreads();  // all waves' vmem drained before arrival
  if (threadIdx.x == 0) {
    int lo = __hip_atomic_fetch_add(&g_bar_leaf[leaf], 1, __ATOMIC_RELAXED, AGT);
    if (lo == LQUOTA - 1) {
      int ro = __hip_atomic_fetch_add(&g_bar_root, 1, __ATOMIC_RELAXED, AGT);
      if (ro == LEAVES - 1) {
        for (int i = 0; i < LEAVES; ++i) ASR(&g_bar_leaf[i], 0);
        ASR(&g_bar_root, 0);
        for (int i = 0; i < LEAVES; ++i)
          __hip_atomic_store(&g_gen[i][0], gen, __ATOMIC_RELEASE, AGT);
      } else {
        while (AL(&g_gen[leaf][0]) < gen) __builtin_amdgcn_s_sleep(2);
      }
    } else {
      while (AL(&g_gen[leaf][0]) < gen) __builtin_amdgcn_s_sleep(2);
    }
  }
  __syncthreads();
}

__device__ __forceinline__ float4 relu4(float4 v) {
  float4 r;
  r.x = fmaxf(v.x, 0.f); r.y = fmaxf(v.y, 0.f);
  r.z = fmaxf(v.z, 0.f); r.w = fmaxf(v.w, 0.f);
  return r;
}

template <int NC>
__device__ __forceinline__ float4 run_rows(const float* const* pp, const float4* uu,
                                           const float* xs) {
  float4 acc = {0.f, 0.f, 0.f, 0.f};
#pragma unroll 8
  for (int r = 0; r < ROWS; ++r) {
    float4 a0 = *(const float4*)(pp[0] + (size_t)r * DD);
    float4 m;
    m.x = a0.x * uu[0].x; m.y = a0.y * uu[0].y;
    m.z = a0.z * uu[0].z; m.w = a0.w * uu[0].w;
#pragma unroll
    for (int c = 1; c < NC; ++c) {
      float4 a = *(const float4*)(pp[c] + (size_t)r * DD);
      m.x = fmaxf(m.x, a.x * uu[c].x);
      m.y = fmaxf(m.y, a.y * uu[c].y);
      m.z = fmaxf(m.z, a.z * uu[c].z);
      m.w = fmaxf(m.w, a.w * uu[c].w);
    }
    const float xr = xs[r];
    acc.x = fmaf(xr, m.x, acc.x);
    acc.y = fmaf(xr, m.y, acc.y);
    acc.z = fmaf(xr, m.z, acc.z);
    acc.w = fmaf(xr, m.w, acc.w);
  }
  return acc;
}

__global__ __launch_bounds__(256, 2) void dep_enc_kernel(
    const float* __restrict__ emb, const float* __restrict__ par,
    const int* __restrict__ cidx, const int* __restrict__ cdep,
    const unsigned char* __restrict__ cmask, float* __restrict__ out) {
  __shared__ int s_ci[NN][CC];
  __shared__ int s_cd[NN][CC];
  __shared__ int s_nc[NN];
  __shared__ int s_pfx[NN];
  __shared__ unsigned char s_reach[NN];
  __shared__ short s_int[NN];  // internal reachable nodes, ascending (= topo)
  __shared__ int s_NI;
  __shared__ int s_flag;
  __shared__ int s_fin;
  __shared__ int s_tick;
  __shared__ float xs[ROWS];

  const int tid = threadIdx.x;
  const int leaf = blockIdx.x & (LEAVES - 1);

  // Start-of-launch acquire: buffer_inv kills stale cross-launch L2 copies of
  // g_z, making later PLAIN cached loads of it safe (first touch of every z
  // line within a launch happens after its node's publish completes).
  if (tid == 0) {
    int dmy = __hip_atomic_load(&g_bar_root, __ATOMIC_ACQUIRE, AGT);
    asm volatile("" ::"v"(dmy));
  }

  // Zero g_z via write-through stores (no L2 allocate -> no stale dirty lines)
  {
    float* zf = &g_z[0][0];
    for (int k = blockIdx.x * 256 + tid; k < NN * DD; k += NB * 256)
      ASR(&zf[k], 0.f);
  }

  // ---- Phase 1 (redundant per block): compact children + prune ----
  if (tid == 0)
    s_flag = (cmask[1021] == 1 && cmask[1022] == 1 && cmask[1023] == 1);
  __syncthreads();
  const bool m_u8 = (s_flag != 0);
  const int* m32 = (const int*)cmask;
  const int i = tid;  // one node per thread
  int nc = 0;
#pragma unroll
  for (int c = 0; c < CC; ++c) {
    bool mk = m_u8 ? (cmask[i * CC + c] != 0) : (m32[i * CC + c] != 0);
    if (mk) {
      s_ci[i][nc] = cidx[i * CC + c];
      s_cd[i][nc] = cdep[i * CC + c];
      ++nc;
    }
  }
  s_nc[i] = nc;
  s_reach[i] = (i == ROOT) ? 1 : 0;
  __syncthreads();

  // Reachability fixpoint (root downward; converges in <= depth passes)
  for (int it = 0; it < NN + 2; ++it) {
    if (tid == 0) s_flag = 0;
    __syncthreads();
    if (s_reach[i] && nc) {
      for (int c = 0; c < nc; ++c)
        if (!s_reach[s_ci[i][c]]) { s_reach[s_ci[i][c]] = 1; s_flag = 1; }
    }
    __syncthreads();
    int ch = s_flag;
    __syncthreads();
    if (!ch) break;
  }

  // Parallel compaction of internal reachable nodes (ascending index = topo)
  const int active = (s_reach[i] && nc > 0) ? 1 : 0;
  s_pfx[i] = active;
  __syncthreads();
  for (int off = 1; off < NN; off <<= 1) {
    int v = (tid >= off) ? s_pfx[tid - off] : 0;
    __syncthreads();
    s_pfx[tid] += v;
    __syncthreads();
  }
  if (active) s_int[s_pfx[i] - 1] = (short)i;
  if (tid == NN - 1) s_NI = s_pfx[NN - 1];
  __syncthreads();

  const int NU = s_NI << 5;  // RS units per internal node
  const int j0 = tid << 2;   // 4 consecutive columns per thread

  // g_z zeroing complete everywhere before any atomicAdd can land
  grid_bar(1, leaf);

  // ---- Phase 2: ticket-driven dataflow units (topo draw order) ----
  for (;;) {
    if (tid == 0)
      s_tick = __hip_atomic_fetch_add(&g_tick, 1, __ATOMIC_RELAXED, AGT);
    __syncthreads();
    const int g = s_tick;
    if (g >= NU) break;

    const int node = s_int[g >> 5];
    const int rblk = g & (RS - 1);
    const int nnc = s_nc[node];

    // xs load overlaps the dependency poll
    if (tid < ROWS) xs[tid] = emb[(size_t)node * DD + rblk * ROWS + tid];
    // Poll children readiness (one thread per child; relaxed -> no cache inv)
    if (tid < nnc) {
      const int chd = s_ci[node][tid];
      if (s_nc[chd] > 0) {
        while (AL(&g_done[chd]) < RS) __builtin_amdgcn_s_sleep(1);
      }
    }
    __syncthreads();  // (A) children ready + xs visible

    // Gather relu(z_child): plain cached coalesced loads (fresh: see inv note)
    float4 uu[CC];
    const float* pp[CC];
    const size_t rb = (size_t)(rblk * ROWS) * DD + j0;
#pragma unroll
    for (int c = 0; c < CC; ++c) {
      if (c < nnc) {
        const int chd = s_ci[node][c];
        pp[c] = par + (size_t)s_cd[node][c] * (DD * DD) + rb;
        float4 sz;
        if (s_nc[chd] == 0) {
          sz = *(const float4*)(emb + (size_t)chd * DD + j0);
        } else {
          sz = *(const float4*)(&g_z[chd][j0]);
        }
        uu[c] = relu4(sz);
      }
    }

    float4 acc;
    switch (nnc) {
      case 1: acc = run_rows<1>(pp, uu, xs); break;
      case 2: acc = run_rows<2>(pp, uu, xs); break;
      case 3: acc = run_rows<3>(pp, uu, xs); break;
      default: acc = run_rows<4>(pp, uu, xs); break;
    }
    // Accumulate partial into z at the memory-side coherence point
    __hip_atomic_fetch_add(&g_z[node][j0 + 0], acc.x, __ATOMIC_RELAXED, AGT);
    __hip_atomic_fetch_add(&g_z[node][j0 + 1], acc.y, __ATOMIC_RELAXED, AGT);
    __hip_atomic_fetch_add(&g_z[node][j0 + 2], acc.z, __ATOMIC_RELAXED, AGT);
    __hip_atomic_fetch_add(&g_z[node][j0 + 3], acc.w, __ATOMIC_RELAXED, AGT);
    __syncthreads();  // (B) all waves' adds drained (vmcnt 0)

    if (tid == 0) {
      int old = __hip_atomic_fetch_add(&g_done[node], 1, __ATOMIC_RELEASE, AGT);
      s_fin = (old == RS - 1 && node == ROOT) ? 1 : 0;
    }
    __syncthreads();  // (C) also protects s_tick rewrite on next draw

    if (s_fin) {
      // Root complete: all adds landed; first (and only) read of root z.
      float4 v = *(const float4*)(&g_z[ROOT][j0]);
      *(float4*)(out + j0) = v;
    }
  }
}

__global__ void reset_kernel() {
  const int t = threadIdx.x;  // 256 threads
  ASR(&g_done[t], 0);
  if (t == 0) ASR(&g_tick, 0);
  if (t < LEAVES) {
    ASR(&g_bar_leaf[t], 0);
    ASR(&g_gen[t][0], 0);
  }
  if (t == 0) ASR(&g_bar_root, 0);
}

extern "C" void kernel_launch(void* const* d_in, const int* in_sizes, int n_in,
                              void* d_out, int out_size, void* d_ws, size_t ws_size,
                              hipStream_t stream) {
  const float* emb = (const float*)d_in[0];
  const float* par = (const float*)d_in[1];
  const int* cidx = (const int*)d_in[2];
  const int* cdep = (const int*)d_in[3];
  const unsigned char* cmask = (const unsigned char*)d_in[4];
  float* out = (float*)d_out;

  hipLaunchKernelGGL(dep_enc_kernel, dim3(NB), dim3(256), 0, stream, emb, par,
                     cidx, cdep, cmask, out);
  hipLaunchKernelGGL(reset_kernel, dim3(1), dim3(256), 0, stream);
}

// Round 10
// 126.128 us; speedup vs baseline: 2.7810x; 2.7810x over previous
//
#include <hip/hip_runtime.h>
#include <cstddef>

#define NN 256
#define DD 1024
#define CC 4
#define NP 46
#define ROOT (NN - 1)
#define TB 64
#define MBLOCKS 256    // main kernel: 256 blocks x 4 columns = 1024 columns
#define MTHREADS 512   // 4 col-groups x 128 threads (8 rows each)

// Transposed params, rebuilt from d_in every launch (no cross-call caching):
// g_Pt[p][j][r] = P[p][r][j]
__device__ float g_Pt[NP][DD][DD];

// ---------------- Kernel 1: tiled transpose (64x64, LDS) ----------------
__global__ __launch_bounds__(256) void transpose_kernel(const float* __restrict__ par) {
  __shared__ float tile[TB][TB + 1];  // +1: bank-conflict pad
  const int b = blockIdx.x;           // p * 256 + tile index
  const int p = b >> 8;
  const int t = b & 255;
  const int tr = (t >> 4) << 6;       // tile row origin in P
  const int tc = (t & 15) << 6;       // tile col origin in P
  const int tid = threadIdx.x;
  const float* src = par + ((size_t)p << 20);
  float* dst = &g_Pt[p][0][0];

  const int lr = tid >> 4;            // 0..15
  const int lc = (tid & 15) << 2;     // 0,4,...,60
#pragma unroll
  for (int k = 0; k < 4; ++k) {
    const int r = lr + (k << 4);
    const float4 v = *(const float4*)(src + (size_t)(tr + r) * DD + tc + lc);
    tile[r][lc + 0] = v.x;
    tile[r][lc + 1] = v.y;
    tile[r][lc + 2] = v.z;
    tile[r][lc + 3] = v.w;
  }
  __syncthreads();
#pragma unroll
  for (int k = 0; k < 4; ++k) {
    const int jj = lr + (k << 4);     // column of P = row of Pt (within tile)
    float4 v;
    v.x = tile[lc + 0][jj];
    v.y = tile[lc + 1][jj];
    v.z = tile[lc + 2][jj];
    v.w = tile[lc + 3][jj];
    *(float4*)(dst + (size_t)(tc + jj) * DD + tr + lc) = v;
  }
}

// ---------------- Kernel 2: column-split serial walk ----------------
struct Stage {
  float4 p[CC][2];  // 8 rows of Pt[dep][j] per (duplicated) child
  float4 x[2];      // 8 rows of emb[node]
  int ci[CC];       // (duplicated) child indices
};

__device__ __forceinline__ void load_stage(Stage& st, int k, const short* s_int,
                                           const int (*s_ci)[CC],
                                           const int (*s_cd)[CC],
                                           const int* s_nc,
                                           const float* __restrict__ emb,
                                           int j, int r0) {
  const int node = s_int[k];
  const int nnc = s_nc[node];
  const float* pt0 = &g_Pt[0][0][0];
#pragma unroll
  for (int c = 0; c < CC; ++c) {
    const int cc = (c < nnc) ? c : 0;  // duplicate child 0: max unchanged
    st.ci[c] = s_ci[node][cc];
    const int dep = s_cd[node][cc];
    const float* base = pt0 + (((size_t)dep) << 20) + ((size_t)j << 10) + r0;
    st.p[c][0] = *(const float4*)(base);
    st.p[c][1] = *(const float4*)(base + 4);
  }
  const float* xb = emb + (((size_t)node) << 10) + r0;
  st.x[0] = *(const float4*)(xb);
  st.x[1] = *(const float4*)(xb + 4);
}

__device__ __forceinline__ void compute_node(const Stage& st, int k,
                                             const short* s_int,
                                             float (*z_loc)[CC], float* s_red,
                                             int tid, int col) {
  const int node = s_int[k];
  float u[CC];
#pragma unroll
  for (int c = 0; c < CC; ++c) u[c] = fmaxf(z_loc[st.ci[c]][col], 0.f);

  float acc = 0.f;
#pragma unroll
  for (int q = 0; q < 2; ++q) {
    float4 m;
    m.x = st.p[0][q].x * u[0];
    m.y = st.p[0][q].y * u[0];
    m.z = st.p[0][q].z * u[0];
    m.w = st.p[0][q].w * u[0];
#pragma unroll
    for (int c = 1; c < CC; ++c) {
      m.x = fmaxf(m.x, st.p[c][q].x * u[c]);
      m.y = fmaxf(m.y, st.p[c][q].y * u[c]);
      m.z = fmaxf(m.z, st.p[c][q].z * u[c]);
      m.w = fmaxf(m.w, st.p[c][q].w * u[c]);
    }
    acc = fmaf(st.x[q].x, m.x, acc);
    acc = fmaf(st.x[q].y, m.y, acc);
    acc = fmaf(st.x[q].z, m.z, acc);
    acc = fmaf(st.x[q].w, m.w, acc);
  }
  // 64-lane butterfly sum (fixed order -> deterministic)
#pragma unroll
  for (int off = 1; off < 64; off <<= 1) acc += __shfl_xor(acc, off, 64);
  if ((tid & 63) == 0) s_red[tid >> 6] = acc;
  __syncthreads();
  if ((tid & 127) == 0) {
    const int c2 = col << 1;
    z_loc[node][col] = s_red[c2] + s_red[c2 + 1];
  }
  __syncthreads();  // z_loc[node] visible to all before next node's u read
}

__global__ __launch_bounds__(MTHREADS, 1) void col_kernel(
    const float* __restrict__ emb, const int* __restrict__ cidx,
    const int* __restrict__ cdep, const unsigned char* __restrict__ cmask,
    float* __restrict__ out) {
  __shared__ int s_ci[NN][CC];
  __shared__ int s_cd[NN][CC];
  __shared__ int s_nc[NN];
  __shared__ int s_pfx[NN];
  __shared__ unsigned char s_reach[NN];
  __shared__ short s_int[NN];  // internal reachable nodes, ascending (= topo)
  __shared__ int s_NI;
  __shared__ int s_flag;
  __shared__ float z_loc[NN][CC];  // z per node, this block's 4 columns
  __shared__ float s_red[8];       // per-wave reduction slots

  const int tid = threadIdx.x;
  const int j0 = blockIdx.x << 2;
  const int col = tid >> 7;   // 0..3
  const int r0 = (tid & 127) << 3;  // 8 rows per thread
  const int j = j0 + col;

  // ---- Phase 1 (per block, LDS only): compact children + prune ----
  if (tid == 0)
    s_flag = (cmask[1021] == 1 && cmask[1022] == 1 && cmask[1023] == 1);
  __syncthreads();
  const bool m_u8 = (s_flag != 0);
  const int* m32 = (const int*)cmask;
  int nc = 0;
  if (tid < NN) {
    const int i = tid;
#pragma unroll
    for (int c = 0; c < CC; ++c) {
      bool mk = m_u8 ? (cmask[i * CC + c] != 0) : (m32[i * CC + c] != 0);
      if (mk) {
        s_ci[i][nc] = cidx[i * CC + c];
        s_cd[i][nc] = cdep[i * CC + c];
        ++nc;
      }
    }
    s_nc[i] = nc;
    s_reach[i] = (i == ROOT) ? 1 : 0;
    // init z_loc from embeddings (leaf value; overwritten for internal nodes)
    float4 e = *(const float4*)(emb + ((size_t)i << 10) + j0);
    z_loc[i][0] = e.x; z_loc[i][1] = e.y; z_loc[i][2] = e.z; z_loc[i][3] = e.w;
  }
  __syncthreads();

  // Reachability fixpoint (root downward; <= depth passes)
  for (int it = 0; it < NN + 2; ++it) {
    if (tid == 0) s_flag = 0;
    __syncthreads();
    if (tid < NN && s_reach[tid] && nc) {
      for (int c = 0; c < nc; ++c)
        if (!s_reach[s_ci[tid][c]]) { s_reach[s_ci[tid][c]] = 1; s_flag = 1; }
    }
    __syncthreads();
    const int ch = s_flag;
    __syncthreads();
    if (!ch) break;
  }

  // Compact internal reachable nodes (ascending index = topological order)
  const int active = (tid < NN && s_reach[tid] && s_nc[tid] > 0) ? 1 : 0;
  if (tid < NN) s_pfx[tid] = active;
  __syncthreads();
  for (int off = 1; off < NN; off <<= 1) {
    int v = 0;
    if (tid < NN && tid >= off) v = s_pfx[tid - off];
    __syncthreads();
    if (tid < NN) s_pfx[tid] += v;
    __syncthreads();
  }
  if (active) s_int[s_pfx[tid] - 1] = (short)tid;
  if (tid == NN - 1) s_NI = s_pfx[NN - 1];
  __syncthreads();
  const int NI = s_NI;

  // ---- Phase 2: serial walk, 2-stage software pipeline (static indexing) ----
  Stage A, B;
  load_stage(A, 0, s_int, s_ci, s_cd, s_nc, emb, j, r0);
  int k = 0;
  while (k < NI) {
    if (k + 1 < NI) load_stage(B, k + 1, s_int, s_ci, s_cd, s_nc, emb, j, r0);
    compute_node(A, k, s_int, z_loc, s_red, tid, col);
    if (++k >= NI) break;
    if (k + 1 < NI) load_stage(A, k + 1, s_int, s_ci, s_cd, s_nc, emb, j, r0);
    compute_node(B, k, s_int, z_loc, s_red, tid, col);
    ++k;
  }

  // ---- Output: root z for this block's 4 columns ----
  if (tid < CC) out[j0 + tid] = z_loc[ROOT][tid];
}

extern "C" void kernel_launch(void* const* d_in, const int* in_sizes, int n_in,
                              void* d_out, int out_size, void* d_ws, size_t ws_size,
                              hipStream_t stream) {
  const float* emb = (const float*)d_in[0];
  const float* par = (const float*)d_in[1];
  const int* cidx = (const int*)d_in[2];
  const int* cdep = (const int*)d_in[3];
  const unsigned char* cmask = (const unsigned char*)d_in[4];
  float* out = (float*)d_out;

  hipLaunchKernelGGL(transpose_kernel, dim3(NP * 256), dim3(256), 0, stream, par);
  hipLaunchKernelGGL(col_kernel, dim3(MBLOCKS), dim3(MTHREADS), 0, stream, emb,
                     cidx, cdep, cmask, out);
}